// Round 1
// baseline (366.707 us; speedup 1.0000x reference)
//
#include <hip/hip_runtime.h>
#include <cstdint>

#define HH 240
#define WW 320
#define CC 64
#define HW (HH * WW)

// 64-bit key: high 32 = depth float bits (positive -> orders as uint),
// low 32 = point index. atomicMin == lexicographic (min depth, then min idx),
// exactly the reference's two-stage winner selection.

__global__ __launch_bounds__(256) void vx_init(unsigned long long* __restrict__ buf, int dump) {
    int i = blockIdx.x * blockDim.x + threadIdx.x;
    if (i < dump) buf[i] = 0xFFFFFFFFFFFFFFFFull;
}

__global__ __launch_bounds__(256) void vx_project(const int4* __restrict__ coords,
                                                  const float* __restrict__ pm,
                                                  unsigned long long* __restrict__ buf,
                                                  int n) {
    int i = blockIdx.x * blockDim.x + threadIdx.x;
    if (i >= n) return;
    int4 c = coords[i];  // (b, z, y, x)
    float x = (float)c.w, y = (float)c.z, z = (float)c.y;
    // ascending-k fma chain (BLAS-like accumulation order)
    float p0 = x * pm[0];
    p0 = fmaf(y, pm[1], p0);
    p0 = fmaf(z, pm[2], p0);
    p0 = p0 + pm[3];
    float p1 = x * pm[4];
    p1 = fmaf(y, pm[5], p1);
    p1 = fmaf(z, pm[6], p1);
    p1 = p1 + pm[7];
    float p2 = x * pm[8];
    p2 = fmaf(y, pm[9], p2);
    p2 = fmaf(z, pm[10], p2);
    p2 = p2 + pm[11];

    if (p2 > 1e-6f) {
        float uf = floorf(p0 / p2);
        float vf = floorf(p1 / p2);
        if (uf >= 0.0f && uf < (float)WW && vf >= 0.0f && vf < (float)HH) {
            int u = (int)uf;
            int v = (int)vf;
            int lin = c.x * HW + v * WW + u;
            unsigned long long pack =
                ((unsigned long long)__float_as_uint(p2) << 32) | (unsigned int)i;
            atomicMin(&buf[lin], pack);
        }
    }
}

__global__ __launch_bounds__(256) void vx_scatter(const unsigned long long* __restrict__ buf,
                                                  const float* __restrict__ feats,
                                                  float* __restrict__ out,
                                                  float* __restrict__ invd,
                                                  int dump) {
    int p = blockIdx.x * blockDim.x + threadIdx.x;
    if (p >= dump) return;
    unsigned long long v = buf[p];
    unsigned int idx = (unsigned int)(v & 0xFFFFFFFFull);
    bool has = (idx != 0xFFFFFFFFu);
    float depth = __uint_as_float((unsigned int)(v >> 32));
    invd[p] = has ? (1.0f / depth) : 0.0f;

    int b = p / HW;
    int pix = p - b * HW;
    float* ob = out + (size_t)b * CC * HW + pix;

    if (has) {
        const float4* row = (const float4*)(feats + (size_t)idx * CC);
#pragma unroll
        for (int c4 = 0; c4 < CC / 4; ++c4) {
            float4 f = row[c4];
            ob[(size_t)(4 * c4 + 0) * HW] = f.x;
            ob[(size_t)(4 * c4 + 1) * HW] = f.y;
            ob[(size_t)(4 * c4 + 2) * HW] = f.z;
            ob[(size_t)(4 * c4 + 3) * HW] = f.w;
        }
    } else {
#pragma unroll
        for (int c = 0; c < CC; ++c) ob[(size_t)c * HW] = 0.0f;
    }
}

extern "C" void kernel_launch(void* const* d_in, const int* in_sizes, int n_in,
                              void* d_out, int out_size, void* d_ws, size_t ws_size,
                              hipStream_t stream) {
    const float* features = (const float*)d_in[0];
    const int4* coords = (const int4*)d_in[1];
    const float* pm = (const float*)d_in[2];
    // batch size known from out_size = B*H*W*(C+1)
    int B = out_size / (HW * (CC + 1));
    int n = in_sizes[1] / 4;
    int dump = B * HW;

    unsigned long long* buf = (unsigned long long*)d_ws;
    float* out = (float*)d_out;
    float* invd = out + (size_t)B * CC * HW;

    vx_init<<<(dump + 255) / 256, 256, 0, stream>>>(buf, dump);
    vx_project<<<(n + 255) / 256, 256, 0, stream>>>(coords, pm, buf, n);
    vx_scatter<<<(dump + 255) / 256, 256, 0, stream>>>(buf, features, out, invd, dump);
}